// Round 1
// baseline (213.007 us; speedup 1.0000x reference)
//
#include <hip/hip_runtime.h>

#define T_LEN 2048
#define DIM 2048
#define NH 16
#define HD 128
#define QKV_LD 6144   // 3*DIM

typedef __attribute__((ext_vector_type(8))) short short8;
typedef __attribute__((ext_vector_type(4))) float f32x4;
typedef __attribute__((ext_vector_type(4))) float float4v;
typedef __attribute__((ext_vector_type(4))) unsigned short ushort4v;

static __device__ __forceinline__ unsigned short f2bf(float f) {
  unsigned u = __builtin_bit_cast(unsigned, f);
  u += 0x7fffu + ((u >> 16) & 1u);   // round-to-nearest-even
  return (unsigned short)(u >> 16);
}

static __device__ __forceinline__ f32x4 mfma16(short8 a, short8 b, f32x4 c) {
  return __builtin_amdgcn_mfma_f32_16x16x32_bf16(a, b, c, 0, 0, 0);
}

#define GLDS16(SRC, DST)                                                            \
  __builtin_amdgcn_global_load_lds((__attribute__((address_space(1))) void*)(SRC),  \
                                   (__attribute__((address_space(3))) void*)(DST),  \
                                   16, 0, 0)

// ---------------------------------------------------------------- cast fp32->bf16
__global__ void cast_f32_bf16(const float* __restrict__ in,
                              unsigned short* __restrict__ out, int n4) {
  int i = blockIdx.x * blockDim.x + threadIdx.x;
  const int stride = gridDim.x * blockDim.x;
  for (; i < n4; i += stride) {
    float4v f = ((const float4v*)in)[i];
    ushort4v o;
    o.x = f2bf(f.x); o.y = f2bf(f.y); o.z = f2bf(f.z); o.w = f2bf(f.w);
    ((ushort4v*)out)[i] = o;
  }
}

// ---------------------------------------------------------------- GEMM: C = A * B^T
// A [M][K] bf16 row-major, B [N][K] bf16 row-major, C [M][N] (bf16 or f32).
// 128x128 tile, BK=64, 4 waves (each 64x64), global_load_lds staging,
// LDS rows 128B with byte ^= ((row&7)<<4) swizzle (pre-swizzled global source).
template <int OUT_BF16>
__global__ __launch_bounds__(256) void gemm_bt_128(
    const unsigned short* __restrict__ A,
    const unsigned short* __restrict__ B,
    void* __restrict__ Cv, int M, int N, int K) {
  __shared__ unsigned short As[128 * 64];
  __shared__ unsigned short Bs[128 * 64];
  const int tid = threadIdx.x;
  const int wave = tid >> 6;
  const int lane = tid & 63;
  const int l15 = lane & 15, l16 = lane >> 4;
  const int bm = blockIdx.y * 128;
  const int bn = blockIdx.x * 128;
  const int wr = wave >> 1, wc = wave & 1;

  f32x4 acc[4][4] = {};

  // staging source (element offsets within the 128x64 tile), inverse-swizzled
  int srow[4], scol[4];
#pragma unroll
  for (int i = 0; i < 4; ++i) {
    int lin = i * 4096 + tid * 16;     // byte index, linear LDS order
    int row = lin >> 7;                // 128B rows
    int cb = lin & 127;
    srow[i] = row;
    scol[i] = (cb ^ ((row & 7) << 4)) >> 1;
  }

  for (int k0 = 0; k0 < K; k0 += 64) {
#pragma unroll
    for (int i = 0; i < 4; ++i) {
      GLDS16(A + (size_t)(bm + srow[i]) * K + k0 + scol[i], As + i * 2048 + wave * 512);
      GLDS16(B + (size_t)(bn + srow[i]) * K + k0 + scol[i], Bs + i * 2048 + wave * 512);
    }
    __syncthreads();
#pragma unroll
    for (int kk = 0; kk < 2; ++kk) {
      const int cb = kk * 64 + l16 * 16;
      short8 af[4], bfr[4];
#pragma unroll
      for (int m = 0; m < 4; ++m) {
        int row = wr * 64 + m * 16 + l15;
        af[m] = *(const short8*)((const char*)As + row * 128 + (cb ^ ((row & 7) << 4)));
      }
#pragma unroll
      for (int n = 0; n < 4; ++n) {
        int row = wc * 64 + n * 16 + l15;
        bfr[n] = *(const short8*)((const char*)Bs + row * 128 + (cb ^ ((row & 7) << 4)));
      }
#pragma unroll
      for (int m = 0; m < 4; ++m)
#pragma unroll
        for (int n = 0; n < 4; ++n)
          acc[m][n] = mfma16(af[m], bfr[n], acc[m][n]);
    }
    __syncthreads();
  }

  // epilogue: C/D layout col=lane&15, row=(lane>>4)*4+j  [m89-verified]
#pragma unroll
  for (int m = 0; m < 4; ++m)
#pragma unroll
    for (int n = 0; n < 4; ++n) {
      int row = bm + wr * 64 + m * 16 + l16 * 4;
      int col = bn + wc * 64 + n * 16 + l15;
#pragma unroll
      for (int j = 0; j < 4; ++j) {
        if (OUT_BF16)
          ((unsigned short*)Cv)[(size_t)(row + j) * N + col] = f2bf(acc[m][n][j]);
        else
          ((float*)Cv)[(size_t)(row + j) * N + col] = acc[m][n][j];
      }
    }
}

// ---------------------------------------------------------------- V transpose
// qkv[s][4096 + h*128 + d] -> vt[h][d][s], 64-s tile per block, swizzled LDS.
__global__ __launch_bounds__(256) void transpose_v(
    const unsigned short* __restrict__ qkv, unsigned short* __restrict__ vt) {
  __shared__ unsigned short t[64 * 128];
  const int tid = threadIdx.x;
  const int h = blockIdx.y;
  const int s0 = blockIdx.x * 64;
#pragma unroll
  for (int i = 0; i < 4; ++i) {
    int lin = i * 2048 + tid * 8;    // element index in 64x128 tile
    int row = lin >> 7, col = lin & 127;
    char* dst = (char*)t + row * 256 + ((col * 2) ^ (((row >> 3) & 7) << 4));
    *(short8*)dst =
        *(const short8*)(qkv + (size_t)(s0 + row) * QKV_LD + 2 * DIM + h * HD + col);
  }
  __syncthreads();
#pragma unroll
  for (int i2 = 0; i2 < 4; ++i2) {
    int d = (tid >> 3) + i2 * 32;
    int sb = (tid & 7) * 8;
    short8 v;
#pragma unroll
    for (int j = 0; j < 8; ++j) {
      int s = sb + j;
      v[j] = *(const short*)((const char*)t + s * 256 + ((d * 2) ^ (((s >> 3) & 7) << 4)));
    }
    *(short8*)(vt + ((size_t)h * HD + d) * T_LEN + s0 + sb) = v;
  }
}

// ---------------------------------------------------------------- flash attention
// Block = 4 waves; wave w owns Q rows [blockIdx.x*64 + w*16, +16), head = blockIdx.y.
// KV tile = 64. K staged [64 s][128 d], V staged transposed [128 d][64 s] (from vt),
// all LDS rows XOR-swizzled. Online softmax in fp32, P through per-wave LDS (bf16).
__global__ __launch_bounds__(256) void attn_fwd(
    const unsigned short* __restrict__ qkv,
    const unsigned short* __restrict__ vt,
    unsigned short* __restrict__ ctx) {
  __shared__ unsigned short Ks[64 * 128];
  __shared__ unsigned short Vs[128 * 64];
  __shared__ unsigned short Ps[4 * 16 * 64];
  const int tid = threadIdx.x;
  const int wave = tid >> 6;
  const int lane = tid & 63;
  const int l15 = lane & 15, l16 = lane >> 4;
  const int h = blockIdx.y;
  const int q0 = blockIdx.x * 64 + wave * 16;
  const float SCL = 0.08838834764831845f * 1.4426950408889634f;  // 1/sqrt(128) * log2(e)

  // hoist Q fragments into registers: Q[q0+l15][kk*32 + l16*8 .. +7]
  short8 qf[4];
#pragma unroll
  for (int kk = 0; kk < 4; ++kk)
    qf[kk] = *(const short8*)(qkv + (size_t)(q0 + l15) * QKV_LD + h * HD + kk * 32 + l16 * 8);

  f32x4 acc_o[8] = {};
  float m_r[4] = {-1e30f, -1e30f, -1e30f, -1e30f};
  float l_r[4] = {0.f, 0.f, 0.f, 0.f};

  // staging source offsets (inverse-swizzled)
  int krow[4], kcol[4], vrow[4], vcol[4];
#pragma unroll
  for (int i = 0; i < 4; ++i) {
    int lin = i * 4096 + tid * 16;
    int r = lin >> 8;                       // K tile: 256B rows
    int cb = lin & 255;
    krow[i] = r; kcol[i] = (cb ^ ((r & 7) << 4)) >> 1;
    r = lin >> 7;                           // V tile: 128B rows
    cb = lin & 127;
    vrow[i] = r; vcol[i] = (cb ^ ((r & 7) << 4)) >> 1;
  }
  const unsigned short* kbase = qkv + 2048 + h * HD;       // K block of qkv
  const unsigned short* vbase = vt + (size_t)h * HD * T_LEN;

  for (int s0 = 0; s0 < T_LEN; s0 += 64) {
#pragma unroll
    for (int i = 0; i < 4; ++i) {
      GLDS16(kbase + (size_t)(s0 + krow[i]) * QKV_LD + kcol[i], Ks + i * 2048 + wave * 512);
      GLDS16(vbase + (size_t)vrow[i] * T_LEN + s0 + vcol[i],    Vs + i * 2048 + wave * 512);
    }
    __syncthreads();

    // S = Q K^T  (16x64 per wave)
    f32x4 sc[4] = {};
#pragma unroll
    for (int c = 0; c < 4; ++c) {
#pragma unroll
      for (int kk = 0; kk < 4; ++kk) {
        int row = c * 16 + l15;
        int cb = kk * 64 + l16 * 16;
        short8 kf = *(const short8*)((const char*)Ks + row * 256 + (cb ^ ((row & 7) << 4)));
        sc[c] = mfma16(qf[kk], kf, sc[c]);
      }
    }

    // online softmax: reduce over s = 4 frags x 16 lanes (same l16 group)
    float tmax[4], tsum[4], corr[4], p[4][4];
#pragma unroll
    for (int j = 0; j < 4; ++j)
      tmax[j] = fmaxf(fmaxf(sc[0][j], sc[1][j]), fmaxf(sc[2][j], sc[3][j])) * SCL;
#pragma unroll
    for (int mask = 1; mask < 16; mask <<= 1)
#pragma unroll
      for (int j = 0; j < 4; ++j)
        tmax[j] = fmaxf(tmax[j], __shfl_xor(tmax[j], mask));
#pragma unroll
    for (int j = 0; j < 4; ++j) {
      float nm = fmaxf(m_r[j], tmax[j]);
      corr[j] = __builtin_amdgcn_exp2f(m_r[j] - nm);
      m_r[j] = nm;
    }
#pragma unroll
    for (int c = 0; c < 4; ++c)
#pragma unroll
      for (int j = 0; j < 4; ++j)
        p[c][j] = __builtin_amdgcn_exp2f(sc[c][j] * SCL - m_r[j]);
#pragma unroll
    for (int j = 0; j < 4; ++j)
      tsum[j] = (p[0][j] + p[1][j]) + (p[2][j] + p[3][j]);
#pragma unroll
    for (int mask = 1; mask < 16; mask <<= 1)
#pragma unroll
      for (int j = 0; j < 4; ++j)
        tsum[j] += __shfl_xor(tsum[j], mask);
#pragma unroll
    for (int j = 0; j < 4; ++j)
      l_r[j] = l_r[j] * corr[j] + tsum[j];
#pragma unroll
    for (int d = 0; d < 8; ++d)
#pragma unroll
      for (int j = 0; j < 4; ++j)
        acc_o[d][j] *= corr[j];

    // P -> per-wave LDS (bf16, swizzled rows of 128B)
    char* pbase = (char*)Ps + wave * 2048;
#pragma unroll
    for (int c = 0; c < 4; ++c)
#pragma unroll
      for (int j = 0; j < 4; ++j) {
        int q = l16 * 4 + j;
        int s = c * 16 + l15;
        *(unsigned short*)(pbase + q * 128 + ((s * 2) ^ ((q & 7) << 4))) = f2bf(p[c][j]);
      }

    // ctx += P @ V  (A = P from LDS, B = V from transposed Vs)
#pragma unroll
    for (int kk = 0; kk < 2; ++kk) {
      int cb = kk * 64 + l16 * 16;
      short8 pa = *(const short8*)(pbase + l15 * 128 + (cb ^ ((l15 & 7) << 4)));
#pragma unroll
      for (int d = 0; d < 8; ++d) {
        int row = d * 16 + l15;
        short8 vb = *(const short8*)((const char*)Vs + row * 128 + (cb ^ ((row & 7) << 4)));
        acc_o[d] = mfma16(pa, vb, acc_o[d]);
      }
    }
    __syncthreads();   // protect Ks/Vs before next stage
  }

  // epilogue: ctx[q][h*128+d] = acc/l
  float rl[4];
#pragma unroll
  for (int j = 0; j < 4; ++j) rl[j] = 1.0f / l_r[j];
#pragma unroll
  for (int d = 0; d < 8; ++d)
#pragma unroll
    for (int j = 0; j < 4; ++j) {
      int row = q0 + l16 * 4 + j;
      int col = h * HD + d * 16 + l15;
      ctx[(size_t)row * DIM + col] = f2bf(acc_o[d][j] * rl[j]);
    }
}

// ---------------------------------------------------------------- launcher
extern "C" void kernel_launch(void* const* d_in, const int* in_sizes, int n_in,
                              void* d_out, int out_size, void* d_ws, size_t ws_size,
                              hipStream_t stream) {
  const float* x = (const float*)d_in[0];
  const float* w_in = (const float*)d_in[1];
  const float* w_out = (const float*)d_in[2];

  char* ws = (char*)d_ws;
  unsigned short* xbf  = (unsigned short*)(ws + 0);          //  8 MB
  unsigned short* wibf = (unsigned short*)(ws + 8388608);    // 24 MB
  unsigned short* wobf = (unsigned short*)(ws + 33554432);   //  8 MB
  unsigned short* qkv  = (unsigned short*)(ws + 41943040);   // 24 MB
  unsigned short* ctx  = (unsigned short*)(ws + 67108864);   //  8 MB
  unsigned short* vt   = (unsigned short*)(ws + 75497472);   //  8 MB  (end: 80 MB)

  cast_f32_bf16<<<2048, 256, 0, stream>>>(x, xbf, (T_LEN * DIM) / 4);
  cast_f32_bf16<<<2048, 256, 0, stream>>>(w_in, wibf, (3 * DIM * DIM) / 4);
  cast_f32_bf16<<<2048, 256, 0, stream>>>(w_out, wobf, (DIM * DIM) / 4);

  // qkv = x @ w_in^T   [2048 x 6144]
  gemm_bt_128<1><<<dim3(48, 16), 256, 0, stream>>>(xbf, wibf, (void*)qkv, T_LEN, 3 * DIM, DIM);
  // vt[h][d][s] = V
  transpose_v<<<dim3(32, 16), 256, 0, stream>>>(qkv, vt);
  // attention -> ctx [2048 x 2048] bf16
  attn_fwd<<<dim3(32, 16), 256, 0, stream>>>(qkv, vt, ctx);
  // out = ctx @ w_out^T  (fp32)
  gemm_bt_128<0><<<dim3(16, 16), 256, 0, stream>>>(ctx, wobf, d_out, T_LEN, DIM, DIM);
}